// Round 6
// baseline (238.898 us; speedup 1.0000x reference)
//
#include <hip/hip_runtime.h>

typedef _Float16 f16;
typedef __attribute__((ext_vector_type(8))) _Float16 f16x8;
typedef __attribute__((ext_vector_type(4))) _Float16 f16x4;
typedef __attribute__((ext_vector_type(4))) float f32x4;

#define MFMA16(a, b, c) __builtin_amdgcn_mfma_f32_16x16x32_f16((a), (b), (c), 0, 0, 0)

// async global->LDS, 16B per lane. LDS base must be WAVE-UNIFORM; HW scatters
// lane i's 16B to base + i*16 (m97/m104).
__device__ __forceinline__ void gld_lds16(const void* g, void* l) {
  __builtin_amdgcn_global_load_lds(
      (__attribute__((address_space(1))) void*)const_cast<void*>(g),
      (__attribute__((address_space(3))) void*)l, 16, 0, 0);
}

__device__ __forceinline__ f16x8 ld8(const f16* p) { return *(const f16x8*)p; }

// ---------------- fused prep: fp32->fp16 X (blocks 0..6143) + W transpose ----
__global__ __launch_bounds__(256) void prep_kernel(
    const float* __restrict__ Q, const float* __restrict__ K, const float* __restrict__ V,
    const float* __restrict__ Wq, const float* __restrict__ Wk,
    const float* __restrict__ Wv, const float* __restrict__ Wo,
    f16* __restrict__ Xq, f16* __restrict__ Xk, f16* __restrict__ Xv,
    f16* __restrict__ Tq, f16* __restrict__ Tk, f16* __restrict__ Tv, f16* __restrict__ To) {
  const int bx = blockIdx.x;
  __shared__ float tile[64][65];
  if (bx < 6144) {  // X conversion: 3 x 2048 blocks x 2048 elems
    const int z = bx >> 11, blk = bx & 2047;
    const float* src = z == 0 ? Q : (z == 1 ? K : V);
    f16* dst = z == 0 ? Xq : (z == 1 ? Xk : Xv);
    size_t i = ((size_t)blk * 256 + threadIdx.x) * 8;
    float4 a = *(const float4*)(src + i);
    float4 b = *(const float4*)(src + i + 4);
    f16x8 h;
    h[0] = (f16)a.x; h[1] = (f16)a.y; h[2] = (f16)a.z; h[3] = (f16)a.w;
    h[4] = (f16)b.x; h[5] = (f16)b.y; h[6] = (f16)b.z; h[7] = (f16)b.w;
    *(f16x8*)(dst + i) = h;
  } else {  // W [K][N] fp32 -> WT [N][K] fp16: 4 x 256 blocks of 64x64 tiles
    const int idx = bx - 6144;
    const int z = idx >> 8, xy = idx & 255;
    const float* W = z == 0 ? Wq : (z == 1 ? Wk : (z == 2 ? Wv : Wo));
    f16* T = z == 0 ? Tq : (z == 1 ? Tk : (z == 2 ? Tv : To));
    const int k0 = (xy & 15) * 64, n0 = (xy >> 4) * 64;
    const int tx = threadIdx.x & 63, ty = threadIdx.x >> 6;
#pragma unroll
    for (int rr = 0; rr < 16; ++rr) {
      int r = rr * 4 + ty;
      tile[r][tx] = W[(size_t)(k0 + r) * 1024 + n0 + tx];
    }
    __syncthreads();
#pragma unroll
    for (int rr = 0; rr < 16; ++rr) {
      int nn = rr * 4 + ty;
      T[(size_t)(n0 + nn) * 1024 + k0 + tx] = (f16)tile[tx][nn];
    }
  }
}

// ---------------- QKV GEMM: 128x128 tile (proven R3 config, 49 us) -----------
// C[4096][1024] = A[4096][1024](f16) * BT^T + bias. grid (32,8,3) = 768 blocks.
// Epilogue: z=0 -> qh [bh][s][64]; z=1 -> kg [bh][r][n][d];
//           z=2 -> vh [bh][s][64] + vtg [bh][r][d][swz(n)].
__global__ __launch_bounds__(256) void gemm_qkv_kernel(
    const f16* __restrict__ Xq, const f16* __restrict__ Xk, const f16* __restrict__ Xv,
    const f16* __restrict__ Bq, const f16* __restrict__ Bk, const f16* __restrict__ Bv,
    const float* __restrict__ bq, const float* __restrict__ bk, const float* __restrict__ bv,
    f16* __restrict__ qh, f16* __restrict__ kg,
    f16* __restrict__ vh, f16* __restrict__ vtg) {
  const int z = blockIdx.z;
  const f16* A = z == 0 ? Xq : (z == 1 ? Xk : Xv);
  const f16* Bt = z == 0 ? Bq : (z == 1 ? Bk : Bv);
  const float* bias = z == 0 ? bq : (z == 1 ? bk : bv);

  __shared__ alignas(16) f16 lA[128 * 32];
  __shared__ alignas(16) f16 lB[128 * 32];

  const int t = threadIdx.x;
  const int w = t >> 6, lane = t & 63, quad = lane >> 4, l15 = lane & 15;
  const int wm = w >> 1, wn = w & 1;
  const int mbase = blockIdx.x * 128;
  const int nbase = blockIdx.y * 128;

  const f32x4 zero4 = {0.f, 0.f, 0.f, 0.f};
  f32x4 acc[4][4];
#pragma unroll
  for (int mi = 0; mi < 4; ++mi)
#pragma unroll
    for (int ni = 0; ni < 4; ++ni) acc[mi][ni] = zero4;

  const int r = t >> 2;            // 0..63
  const int koff = (t & 3) * 8;    // f16 offset 0,8,16,24

  for (int k0 = 0; k0 < 1024; k0 += 32) {
    __syncthreads();
    gld_lds16(A + (size_t)(mbase + r) * 1024 + k0 + koff, (char*)lA + w * 1024);
    gld_lds16(A + (size_t)(mbase + 64 + r) * 1024 + k0 + koff, (char*)lA + 4096 + w * 1024);
    gld_lds16(Bt + (size_t)(nbase + r) * 1024 + k0 + koff, (char*)lB + w * 1024);
    gld_lds16(Bt + (size_t)(nbase + 64 + r) * 1024 + k0 + koff, (char*)lB + 4096 + w * 1024);
    __syncthreads();

    f16x8 af[4], bf[4];
#pragma unroll
    for (int mi = 0; mi < 4; ++mi)
      af[mi] = ld8(&lA[(wm * 64 + mi * 16 + l15) * 32 + quad * 8]);
#pragma unroll
    for (int ni = 0; ni < 4; ++ni)
      bf[ni] = ld8(&lB[(wn * 64 + ni * 16 + l15) * 32 + quad * 8]);
#pragma unroll
    for (int mi = 0; mi < 4; ++mi)
#pragma unroll
      for (int ni = 0; ni < 4; ++ni)
        acc[mi][ni] = MFMA16(af[mi], bf[ni], acc[mi][ni]);
  }

  // epilogue. C/D layout: col=lane&15, row=quad*4+reg (m89/m91).
#pragma unroll
  for (int mi = 0; mi < 4; ++mi) {
#pragma unroll
    for (int ni = 0; ni < 4; ++ni) {
#pragma unroll
      for (int rg = 0; rg < 4; ++rg) {
        const int row = mbase + wm * 64 + mi * 16 + quad * 4 + rg;
        const int col = nbase + wn * 64 + ni * 16 + l15;
        const float v = acc[mi][ni][rg] + bias[col];
        const int bh = (row >> 10) * 16 + (col >> 6);
        const int s = row & 1023, d = col & 63;
        const f16 hv = (f16)v;
        if (z == 0) {
          qh[(size_t)bh * 65536 + s * 64 + d] = hv;
        } else if (z == 1) {
          // class-gathered K only: [bh][r=s&3][n=s>>2][d] (32B-contig runs)
          kg[(((size_t)bh * 4 + (s & 3)) * 256 + (s >> 2)) * 64 + d] = hv;
        } else {
          vh[(size_t)bh * 65536 + s * 64 + d] = hv;
          // vtg: [bh][r][d][swz(n)], n -> (n&15)*4 + ((n&63)>>4) in 64-blocks
          const int rr = s & 3, n = s >> 2, wi = n & 63;
          vtg[(size_t)bh * 65536 + (size_t)rr * 16384 + (size_t)d * 256 +
              (n & ~63) + ((wi & 15) << 2) + (wi >> 4)] = hv;
        }
      }
    }
  }
}

// ---------------- out-projection GEMM: 64x128 tile, 512 blocks (R4 config) ---
__global__ __launch_bounds__(256) void gemm_out_kernel(
    const f16* __restrict__ A, const f16* __restrict__ Bt,
    const float* __restrict__ bias, float* __restrict__ Cf) {
  __shared__ alignas(16) f16 lA[64 * 32];
  __shared__ alignas(16) f16 lB[128 * 32];

  const int t = threadIdx.x;
  const int w = t >> 6, lane = t & 63, quad = lane >> 4, l15 = lane & 15;
  const int wm = w >> 1, wn = w & 1;  // wave tile 32m x 64n
  const int mbase = blockIdx.x * 64;
  const int nbase = blockIdx.y * 128;

  const f32x4 zero4 = {0.f, 0.f, 0.f, 0.f};
  f32x4 acc[2][4];
#pragma unroll
  for (int mi = 0; mi < 2; ++mi)
#pragma unroll
    for (int ni = 0; ni < 4; ++ni) acc[mi][ni] = zero4;

  const int r = t >> 2;
  const int koff = (t & 3) * 8;

  for (int k0 = 0; k0 < 1024; k0 += 32) {
    __syncthreads();
    gld_lds16(A + (size_t)(mbase + r) * 1024 + k0 + koff, (char*)lA + w * 1024);
    gld_lds16(Bt + (size_t)(nbase + r) * 1024 + k0 + koff, (char*)lB + w * 1024);
    gld_lds16(Bt + (size_t)(nbase + 64 + r) * 1024 + k0 + koff, (char*)lB + 4096 + w * 1024);
    __syncthreads();

    f16x8 af[2], bf[4];
#pragma unroll
    for (int mi = 0; mi < 2; ++mi)
      af[mi] = ld8(&lA[(wm * 32 + mi * 16 + l15) * 32 + quad * 8]);
#pragma unroll
    for (int ni = 0; ni < 4; ++ni)
      bf[ni] = ld8(&lB[(wn * 64 + ni * 16 + l15) * 32 + quad * 8]);
#pragma unroll
    for (int mi = 0; mi < 2; ++mi)
#pragma unroll
      for (int ni = 0; ni < 4; ++ni)
        acc[mi][ni] = MFMA16(af[mi], bf[ni], acc[mi][ni]);
  }

#pragma unroll
  for (int mi = 0; mi < 2; ++mi)
#pragma unroll
    for (int ni = 0; ni < 4; ++ni)
#pragma unroll
      for (int rg = 0; rg < 4; ++rg) {
        const int row = mbase + wm * 32 + mi * 16 + quad * 4 + rg;
        const int col = nbase + wn * 64 + ni * 16 + l15;
        Cf[(size_t)row * 1024 + col] = acc[mi][ni][rg] + bias[col];
      }
}

// ---------------- far-field attention (strided part: j<=i-4, (i-j)%4==0) -----
// Class space (i=4m+r, j=4n+r): pure causal n<m over 256-length sequences.
// One wave = 16 q-rows of one (bh,r) -> 4096 wave-units, 1024 blocks x 4 waves
// (2x the R5 TLP: 4 waves/SIMD in a latency-bound kernel). widx = blockIdx.x +
// 1024*w -> every block gets tile counts {1,2,3,4} = 10 units (balance).
// NO barriers, NO staging LDS. K from kg (contig rows), V from vtg (swizzled).
// Per-wave LDS only for the P C->A-layout transpose (stride 72).
__global__ __launch_bounds__(256) void attn_far_kernel(
    const f16* __restrict__ qh, const f16* __restrict__ kg,
    const f16* __restrict__ vtg, float* __restrict__ po, float* __restrict__ ml) {
  const int t = threadIdx.x;
  const int w = t >> 6, lane = t & 63, quad = lane >> 4, l15 = lane & 15;
  const int widx = blockIdx.x + 1024 * w;
  const int bh = (widx & 255) >> 2, r = widx & 3;
  const int wq = widx >> 8;          // 0..15, 16 class-rows each
  const int m0 = wq * 16;
  const int ntiles = (wq >> 2) + 1;  // key tiles covering n < m0+16

  __shared__ alignas(16) f16 lp[4][16 * 72];

  const f16* qb = qh + (size_t)bh * 65536;
  const f16* kb = kg + ((size_t)bh * 4 + r) * 16384;             // [n][d]
  const f16* vb = vtg + (size_t)bh * 65536 + (size_t)r * 16384;  // [d][swz n]
  const float SCL2 = 0.125f * 1.44269504f;  // 1/sqrt(64) * log2(e)

  const f16* qrow = qb + (size_t)(4 * (m0 + l15) + r) * 64;
  const f16x8 aq0 = ld8(qrow + quad * 8);
  const f16x8 aq1 = ld8(qrow + 32 + quad * 8);

  const f32x4 zero4 = {0.f, 0.f, 0.f, 0.f};
  f32x4 o[4];
  float mrun[4], lrun[4];
#pragma unroll
  for (int i = 0; i < 4; ++i) { o[i] = zero4; mrun[i] = -1e30f; lrun[i] = 0.f; }

  for (int jt = 0; jt < ntiles; ++jt) {
    const int n0 = jt * 64;
    f16x8 bk0[4], bk1[4], bv0[4], bv1[4];
#pragma unroll
    for (int nt = 0; nt < 4; ++nt) {
      const f16* kr = kb + (size_t)(n0 + nt * 16 + l15) * 64;  // contig rows
      bk0[nt] = ld8(kr + quad * 8);
      bk1[nt] = ld8(kr + 32 + quad * 8);
      const f16* vr = vb + (size_t)(nt * 16 + l15) * 256 + n0;  // swizzled keys
      bv0[nt] = ld8(vr + quad * 8);
      bv1[nt] = ld8(vr + 32 + quad * 8);
    }
    f32x4 sc[4];
#pragma unroll
    for (int nt = 0; nt < 4; ++nt) {
      f32x4 c = MFMA16(aq0, bk0[nt], zero4);
      sc[nt] = MFMA16(aq1, bk1[nt], c);
    }
    const bool lastt = (jt == ntiles - 1);  // only tile needing the n<m mask
#pragma unroll
    for (int rg = 0; rg < 4; ++rg) {
      const int m = m0 + quad * 4 + rg;
      float s[4];
#pragma unroll
      for (int nt = 0; nt < 4; ++nt) {
        float vsc = sc[nt][rg] * SCL2;
        // -3e38 (not -1e30): all-masked rows (m=0) must give p==0 exactly
        if (lastt) vsc = (n0 + nt * 16 + l15 < m) ? vsc : -3.0e38f;
        s[nt] = vsc;
      }
      float tm = fmaxf(fmaxf(s[0], s[1]), fmaxf(s[2], s[3]));
      tm = fmaxf(tm, __shfl_xor(tm, 1));
      tm = fmaxf(tm, __shfl_xor(tm, 2));
      tm = fmaxf(tm, __shfl_xor(tm, 4));
      tm = fmaxf(tm, __shfl_xor(tm, 8));
      const float mnew = fmaxf(mrun[rg], tm);
      const float alpha = exp2f(mrun[rg] - mnew);
      float p[4], ps = 0.f;
#pragma unroll
      for (int nt = 0; nt < 4; ++nt) { p[nt] = exp2f(s[nt] - mnew); ps += p[nt]; }
      ps += __shfl_xor(ps, 1);
      ps += __shfl_xor(ps, 2);
      ps += __shfl_xor(ps, 4);
      ps += __shfl_xor(ps, 8);
      lrun[rg] = lrun[rg] * alpha + ps;
      mrun[rg] = mnew;
#pragma unroll
      for (int ntv = 0; ntv < 4; ++ntv) o[ntv][rg] *= alpha;
      // P store at swizzled key pos l15*4+nt (8B, lane-contiguous)
      f16x4 pk;
      pk.x = (f16)p[0]; pk.y = (f16)p[1]; pk.z = (f16)p[2]; pk.w = (f16)p[3];
      *(f16x4*)&lp[w][(quad * 4 + rg) * 72 + l15 * 4] = pk;
    }
    // PV (same-wave LDS produce->consume; compiler inserts lgkmcnt)
    const f16x8 ap0 = ld8(&lp[w][l15 * 72 + quad * 8]);
    const f16x8 ap1 = ld8(&lp[w][l15 * 72 + 32 + quad * 8]);
#pragma unroll
    for (int ntv = 0; ntv < 4; ++ntv) {
      f32x4 c = MFMA16(ap0, bv0[ntv], o[ntv]);
      o[ntv] = MFMA16(ap1, bv1[ntv], c);
    }
  }

  // write unnormalized partials (merged by attn_diag_kernel)
#pragma unroll
  for (int rg = 0; rg < 4; ++rg) {
    const int i = 4 * (m0 + quad * 4 + rg) + r;
    const size_t idx = (size_t)bh * 1024 + i;
#pragma unroll
    for (int ntv = 0; ntv < 4; ++ntv)
      po[idx * 64 + ntv * 16 + l15] = o[ntv][rg];
    if (l15 == 0) { ml[idx * 2] = mrun[rg]; ml[idx * 2 + 1] = lrun[rg]; }
  }
}

// ---------------- diagonal band (d=0..3) + merge with far partials -----------
// K is read through kg's class permutation (row j = kg[bh][j&3][j>>2]) --
// still lane-contiguous in d, saving a separate kh buffer entirely.
__global__ __launch_bounds__(256) void attn_diag_kernel(
    const f16* __restrict__ qh, const f16* __restrict__ kg, const f16* __restrict__ vh,
    const float* __restrict__ po, const float* __restrict__ ml, f16* __restrict__ ao) {
  const int t = threadIdx.x;
  const int widx = blockIdx.x * 4 + (t >> 6);
  const int l = t & 63;
  const int bh = widx >> 10, i = widx & 1023;
  const float SCL2 = 0.125f * 1.44269504f;

  const float q = (float)qh[(size_t)bh * 65536 + (size_t)i * 64 + l];
  float s[4];
#pragma unroll
  for (int d = 0; d < 4; ++d) {
    const int j = i - d;
    const int jc = j < 0 ? 0 : j;
    float pr = q * (float)kg[(((size_t)bh * 4 + (jc & 3)) * 256 + (jc >> 2)) * 64 + l];
    pr += __shfl_xor(pr, 1);
    pr += __shfl_xor(pr, 2);
    pr += __shfl_xor(pr, 4);
    pr += __shfl_xor(pr, 8);
    pr += __shfl_xor(pr, 16);
    pr += __shfl_xor(pr, 32);
    s[d] = (j >= 0) ? pr * SCL2 : -3.0e38f;
  }
  const float md = fmaxf(fmaxf(s[0], s[1]), fmaxf(s[2], s[3]));
  const size_t idx = (size_t)bh * 1024 + i;
  const float mf = ml[idx * 2], lf = ml[idx * 2 + 1];
  const float M = fmaxf(md, mf);
  float p[4], ld = 0.f;
#pragma unroll
  for (int d = 0; d < 4; ++d) { p[d] = exp2f(s[d] - M); ld += p[d]; }
  float ov = 0.f;
#pragma unroll
  for (int d = 0; d < 4; ++d) {
    const int jc = (i - d) < 0 ? 0 : (i - d);
    ov += p[d] * (float)vh[(size_t)bh * 65536 + (size_t)jc * 64 + l];
  }
  const float fs = exp2f(mf - M);  // mf=-1e30 (empty far set) -> 0
  const float lt = lf * fs + ld;
  const float of = po[idx * 64 + l];
  const float res = (of * fs + ov) / lt;
  const int b = bh >> 4, h = bh & 15;
  ao[((size_t)(b * 1024 + i)) * 1024 + h * 64 + l] = (f16)res;
}

// ---------------------------------------------------------------------------
extern "C" void kernel_launch(void* const* d_in, const int* in_sizes, int n_in,
                              void* d_out, int out_size, void* d_ws, size_t ws_size,
                              hipStream_t stream) {
  const float* Q = (const float*)d_in[0];
  const float* K = (const float*)d_in[1];
  const float* V = (const float*)d_in[2];
  const float* Wq = (const float*)d_in[3];
  const float* bq = (const float*)d_in[4];
  const float* Wk = (const float*)d_in[5];
  const float* bk = (const float*)d_in[6];
  const float* Wv = (const float*)d_in[7];
  const float* bv = (const float*)d_in[8];
  const float* Wo = (const float*)d_in[9];
  const float* bo = (const float*)d_in[10];
  float* out = (float*)d_out;

  char* ws = (char*)d_ws;
  const size_t MB = 1ull << 20;
  // Live-range-overlapped layout, 64 MB total:
  f16* TWo = (f16*)(ws + 0 * MB);      // live until out-proj
  f16* TWq = (f16*)(ws + 2 * MB);      // dead after QKV gemm
  f16* TWk = (f16*)(ws + 4 * MB);
  f16* TWv = (f16*)(ws + 6 * MB);
  f16* Xq  = (f16*)(ws + 8 * MB);      // dead after QKV gemm
  f16* Xk  = (f16*)(ws + 16 * MB);
  f16* Xv  = (f16*)(ws + 24 * MB);
  f16* qhb = (f16*)(ws + 32 * MB);     // [bh][s][64]     (far + diag)
  f16* vhb = (f16*)(ws + 40 * MB);     // [bh][s][64]     (diag)
  f16* kgb = (f16*)(ws + 48 * MB);     // [bh][r][n][d]   (far + diag)
  f16* vtg = (f16*)(ws + 56 * MB);     // [bh][r][d][swz] (far; dead after)
  float* po  = (float*)(ws + 8 * MB);  // 16 MB over dead Xq+Xk (post-QKV)
  float* mlb = (float*)(ws + 24 * MB); // 0.5 MB over dead Xv head
  f16* aob   = (f16*)(ws + 56 * MB);   // 8 MB over vtg (dead post-far)

  prep_kernel<<<dim3(7168), 256, 0, stream>>>(
      Q, K, V, Wq, Wk, Wv, Wo, Xq, Xk, Xv, TWq, TWk, TWv, TWo);
  gemm_qkv_kernel<<<dim3(32, 8, 3), 256, 0, stream>>>(
      Xq, Xk, Xv, TWq, TWk, TWv, bq, bk, bv, qhb, kgb, vhb, vtg);
  attn_far_kernel<<<dim3(1024), 256, 0, stream>>>(qhb, kgb, vtg, po, mlb);
  attn_diag_kernel<<<dim3(16384), 256, 0, stream>>>(qhb, kgb, vhb, po, mlb, aob);
  gemm_out_kernel<<<dim3(64, 8), 256, 0, stream>>>(aob, TWo, bo, out);
}

// Round 7
// 238.890 us; speedup vs baseline: 1.0000x; 1.0000x over previous
//
#include <hip/hip_runtime.h>

typedef _Float16 f16;
typedef __attribute__((ext_vector_type(8))) _Float16 f16x8;
typedef __attribute__((ext_vector_type(4))) _Float16 f16x4;
typedef __attribute__((ext_vector_type(4))) float f32x4;

#define MFMA16(a, b, c) __builtin_amdgcn_mfma_f32_16x16x32_f16((a), (b), (c), 0, 0, 0)

// async global->LDS, 16B per lane. LDS base must be WAVE-UNIFORM; HW scatters
// lane i's 16B to base + i*16 (m97/m104).
__device__ __forceinline__ void gld_lds16(const void* g, void* l) {
  __builtin_amdgcn_global_load_lds(
      (__attribute__((address_space(1))) void*)const_cast<void*>(g),
      (__attribute__((address_space(3))) void*)l, 16, 0, 0);
}

__device__ __forceinline__ f16x8 ld8(const f16* p) { return *(const f16x8*)p; }

// ---------------- fused prep: fp32->fp16 X (blocks 0..6143) + W transpose ----
__global__ __launch_bounds__(256) void prep_kernel(
    const float* __restrict__ Q, const float* __restrict__ K, const float* __restrict__ V,
    const float* __restrict__ Wq, const float* __restrict__ Wk,
    const float* __restrict__ Wv, const float* __restrict__ Wo,
    f16* __restrict__ Xq, f16* __restrict__ Xk, f16* __restrict__ Xv,
    f16* __restrict__ Tq, f16* __restrict__ Tk, f16* __restrict__ Tv, f16* __restrict__ To) {
  const int bx = blockIdx.x;
  __shared__ float tile[64][65];
  if (bx < 6144) {  // X conversion: 3 x 2048 blocks x 2048 elems
    const int z = bx >> 11, blk = bx & 2047;
    const float* src = z == 0 ? Q : (z == 1 ? K : V);
    f16* dst = z == 0 ? Xq : (z == 1 ? Xk : Xv);
    size_t i = ((size_t)blk * 256 + threadIdx.x) * 8;
    float4 a = *(const float4*)(src + i);
    float4 b = *(const float4*)(src + i + 4);
    f16x8 h;
    h[0] = (f16)a.x; h[1] = (f16)a.y; h[2] = (f16)a.z; h[3] = (f16)a.w;
    h[4] = (f16)b.x; h[5] = (f16)b.y; h[6] = (f16)b.z; h[7] = (f16)b.w;
    *(f16x8*)(dst + i) = h;
  } else {  // W [K][N] fp32 -> WT [N][K] fp16: 4 x 256 blocks of 64x64 tiles
    const int idx = bx - 6144;
    const int z = idx >> 8, xy = idx & 255;
    const float* W = z == 0 ? Wq : (z == 1 ? Wk : (z == 2 ? Wv : Wo));
    f16* T = z == 0 ? Tq : (z == 1 ? Tk : (z == 2 ? Tv : To));
    const int k0 = (xy & 15) * 64, n0 = (xy >> 4) * 64;
    const int tx = threadIdx.x & 63, ty = threadIdx.x >> 6;
#pragma unroll
    for (int rr = 0; rr < 16; ++rr) {
      int r = rr * 4 + ty;
      tile[r][tx] = W[(size_t)(k0 + r) * 1024 + n0 + tx];
    }
    __syncthreads();
#pragma unroll
    for (int rr = 0; rr < 16; ++rr) {
      int nn = rr * 4 + ty;
      T[(size_t)(n0 + nn) * 1024 + k0 + tx] = (f16)tile[tx][nn];
    }
  }
}

// ---------------- QKV GEMM: 128x128 tile, R3-proven 49us epilogue ------------
// C[4096][1024] = A[4096][1024](f16) * BT^T + bias. grid (32,8,3) = 768 blocks.
// Epilogue (R3 config -- coalesced kh, NOT class-gathered kg; kg's rg-loop
// sprays 4 r-planes and cost +16us in R6):
//   z=0 -> qh [bh][s][64]; z=1 -> kh [bh][s][64];
//   z=2 -> vh [bh][s][64] + vtg [bh][r][d][swz(n)].
__global__ __launch_bounds__(256) void gemm_qkv_kernel(
    const f16* __restrict__ Xq, const f16* __restrict__ Xk, const f16* __restrict__ Xv,
    const f16* __restrict__ Bq, const f16* __restrict__ Bk, const f16* __restrict__ Bv,
    const float* __restrict__ bq, const float* __restrict__ bk, const float* __restrict__ bv,
    f16* __restrict__ qh, f16* __restrict__ kh,
    f16* __restrict__ vh, f16* __restrict__ vtg) {
  const int z = blockIdx.z;
  const f16* A = z == 0 ? Xq : (z == 1 ? Xk : Xv);
  const f16* Bt = z == 0 ? Bq : (z == 1 ? Bk : Bv);
  const float* bias = z == 0 ? bq : (z == 1 ? bk : bv);

  __shared__ alignas(16) f16 lA[128 * 32];
  __shared__ alignas(16) f16 lB[128 * 32];

  const int t = threadIdx.x;
  const int w = t >> 6, lane = t & 63, quad = lane >> 4, l15 = lane & 15;
  const int wm = w >> 1, wn = w & 1;
  const int mbase = blockIdx.x * 128;
  const int nbase = blockIdx.y * 128;

  const f32x4 zero4 = {0.f, 0.f, 0.f, 0.f};
  f32x4 acc[4][4];
#pragma unroll
  for (int mi = 0; mi < 4; ++mi)
#pragma unroll
    for (int ni = 0; ni < 4; ++ni) acc[mi][ni] = zero4;

  const int r = t >> 2;            // 0..63
  const int koff = (t & 3) * 8;    // f16 offset 0,8,16,24

  for (int k0 = 0; k0 < 1024; k0 += 32) {
    __syncthreads();
    gld_lds16(A + (size_t)(mbase + r) * 1024 + k0 + koff, (char*)lA + w * 1024);
    gld_lds16(A + (size_t)(mbase + 64 + r) * 1024 + k0 + koff, (char*)lA + 4096 + w * 1024);
    gld_lds16(Bt + (size_t)(nbase + r) * 1024 + k0 + koff, (char*)lB + w * 1024);
    gld_lds16(Bt + (size_t)(nbase + 64 + r) * 1024 + k0 + koff, (char*)lB + 4096 + w * 1024);
    __syncthreads();

    f16x8 af[4], bf[4];
#pragma unroll
    for (int mi = 0; mi < 4; ++mi)
      af[mi] = ld8(&lA[(wm * 64 + mi * 16 + l15) * 32 + quad * 8]);
#pragma unroll
    for (int ni = 0; ni < 4; ++ni)
      bf[ni] = ld8(&lB[(wn * 64 + ni * 16 + l15) * 32 + quad * 8]);
#pragma unroll
    for (int mi = 0; mi < 4; ++mi)
#pragma unroll
      for (int ni = 0; ni < 4; ++ni)
        acc[mi][ni] = MFMA16(af[mi], bf[ni], acc[mi][ni]);
  }

  // epilogue. C/D layout: col=lane&15, row=quad*4+reg (m89/m91).
#pragma unroll
  for (int mi = 0; mi < 4; ++mi) {
#pragma unroll
    for (int ni = 0; ni < 4; ++ni) {
#pragma unroll
      for (int rg = 0; rg < 4; ++rg) {
        const int row = mbase + wm * 64 + mi * 16 + quad * 4 + rg;
        const int col = nbase + wn * 64 + ni * 16 + l15;
        const float v = acc[mi][ni][rg] + bias[col];
        const int bh = (row >> 10) * 16 + (col >> 6);
        const int s = row & 1023, d = col & 63;
        const f16 hv = (f16)v;
        if (z == 0) {
          qh[(size_t)bh * 65536 + s * 64 + d] = hv;
        } else if (z == 1) {
          kh[(size_t)bh * 65536 + s * 64 + d] = hv;
        } else {
          vh[(size_t)bh * 65536 + s * 64 + d] = hv;
          // vtg: [bh][r][d][swz(n)], n -> (n&15)*4 + ((n&63)>>4) in 64-blocks
          const int rr = s & 3, n = s >> 2, wi = n & 63;
          vtg[(size_t)bh * 65536 + (size_t)rr * 16384 + (size_t)d * 256 +
              (n & ~63) + ((wi & 15) << 2) + (wi >> 4)] = hv;
        }
      }
    }
  }
}

// ---------------- out-projection GEMM: 64x128 tile, 512 blocks ---------------
__global__ __launch_bounds__(256) void gemm_out_kernel(
    const f16* __restrict__ A, const f16* __restrict__ Bt,
    const float* __restrict__ bias, float* __restrict__ Cf) {
  __shared__ alignas(16) f16 lA[64 * 32];
  __shared__ alignas(16) f16 lB[128 * 32];

  const int t = threadIdx.x;
  const int w = t >> 6, lane = t & 63, quad = lane >> 4, l15 = lane & 15;
  const int wm = w >> 1, wn = w & 1;  // wave tile 32m x 64n
  const int mbase = blockIdx.x * 64;
  const int nbase = blockIdx.y * 128;

  const f32x4 zero4 = {0.f, 0.f, 0.f, 0.f};
  f32x4 acc[2][4];
#pragma unroll
  for (int mi = 0; mi < 2; ++mi)
#pragma unroll
    for (int ni = 0; ni < 4; ++ni) acc[mi][ni] = zero4;

  const int r = t >> 2;
  const int koff = (t & 3) * 8;

  for (int k0 = 0; k0 < 1024; k0 += 32) {
    __syncthreads();
    gld_lds16(A + (size_t)(mbase + r) * 1024 + k0 + koff, (char*)lA + w * 1024);
    gld_lds16(Bt + (size_t)(nbase + r) * 1024 + k0 + koff, (char*)lB + w * 1024);
    gld_lds16(Bt + (size_t)(nbase + 64 + r) * 1024 + k0 + koff, (char*)lB + 4096 + w * 1024);
    __syncthreads();

    f16x8 af[2], bf[4];
#pragma unroll
    for (int mi = 0; mi < 2; ++mi)
      af[mi] = ld8(&lA[(wm * 32 + mi * 16 + l15) * 32 + quad * 8]);
#pragma unroll
    for (int ni = 0; ni < 4; ++ni)
      bf[ni] = ld8(&lB[(wn * 64 + ni * 16 + l15) * 32 + quad * 8]);
#pragma unroll
    for (int mi = 0; mi < 2; ++mi)
#pragma unroll
      for (int ni = 0; ni < 4; ++ni)
        acc[mi][ni] = MFMA16(af[mi], bf[ni], acc[mi][ni]);
  }

#pragma unroll
  for (int mi = 0; mi < 2; ++mi)
#pragma unroll
    for (int ni = 0; ni < 4; ++ni)
#pragma unroll
      for (int rg = 0; rg < 4; ++rg) {
        const int row = mbase + wm * 32 + mi * 16 + quad * 4 + rg;
        const int col = nbase + wn * 64 + ni * 16 + l15;
        Cf[(size_t)row * 1024 + col] = acc[mi][ni][rg] + bias[col];
      }
}

// ---------------- far-field attention (strided part: j<=i-4, (i-j)%4==0) -----
// R3-proven kernel: class space (i=4m+r, j=4n+r) is pure causal n<m over
// 256-length sequences. One wave = 32 q-rows of one (bh,r); key tiles of 64
// class-keys; NO barriers, NO staging LDS. K B-frags strided from kh; V
// B-frags from pre-transposed swizzled vtg. Per-wave LDS only for the P
// C->A-layout transpose (stride 72). widx = blockIdx.x + 512*w -> every block
// gets tile counts {1,2,3,4} = 10 units (static balance).
__global__ __launch_bounds__(256) void attn_far_kernel(
    const f16* __restrict__ qh, const f16* __restrict__ kh,
    const f16* __restrict__ vtg, float* __restrict__ po, float* __restrict__ ml) {
  const int t = threadIdx.x;
  const int w = t >> 6, lane = t & 63, quad = lane >> 4, l15 = lane & 15;
  const int widx = blockIdx.x + 512 * w;
  const int bh = (widx & 255) >> 2, r = widx & 3;
  const int wq = widx >> 8;          // 0..7, 32 class-rows each
  const int m0 = wq * 32;
  const int ntiles = (wq >> 1) + 1;  // key tiles covering n < m0+32

  __shared__ alignas(16) f16 lp[4][2][16 * 72];

  const f16* qb = qh + (size_t)bh * 65536;
  const f16* kb = kh + (size_t)bh * 65536;
  const f16* vb = vtg + (size_t)bh * 65536 + (size_t)r * 16384;  // [d][swz n]
  const float SCL2 = 0.125f * 1.44269504f;  // 1/sqrt(64) * log2(e)

  f16x8 aq[2][2];
#pragma unroll
  for (int mt = 0; mt < 2; ++mt) {
    const int i = 4 * (m0 + mt * 16 + l15) + r;
#pragma unroll
    for (int ko = 0; ko < 2; ++ko)
      aq[mt][ko] = ld8(qb + (size_t)i * 64 + ko * 32 + quad * 8);
  }

  const f32x4 zero4 = {0.f, 0.f, 0.f, 0.f};
  f32x4 o[2][4];
  float mrun[2][4], lrun[2][4];
#pragma unroll
  for (int mt = 0; mt < 2; ++mt)
#pragma unroll
    for (int i = 0; i < 4; ++i) {
      o[mt][i] = zero4; mrun[mt][i] = -1e30f; lrun[mt][i] = 0.f;
    }

  for (int jt = 0; jt < ntiles; ++jt) {
    const int n0 = jt * 64;
    f16x8 bk0[4], bk1[4], bv0[4], bv1[4];
#pragma unroll
    for (int nt = 0; nt < 4; ++nt) {
      const f16* kr = kb + (size_t)(4 * (n0 + nt * 16 + l15) + r) * 64;
      bk0[nt] = ld8(kr + quad * 8);
      bk1[nt] = ld8(kr + 32 + quad * 8);
      const f16* vr = vb + (size_t)(nt * 16 + l15) * 256 + n0;  // swizzled keys
      bv0[nt] = ld8(vr + quad * 8);
      bv1[nt] = ld8(vr + 32 + quad * 8);
    }
    const bool lastt = (jt == ntiles - 1);  // only tile needing the n<m mask
#pragma unroll
    for (int mt = 0; mt < 2; ++mt) {
      f32x4 sc[4];
#pragma unroll
      for (int nt = 0; nt < 4; ++nt) {
        f32x4 c = MFMA16(aq[mt][0], bk0[nt], zero4);
        sc[nt] = MFMA16(aq[mt][1], bk1[nt], c);
      }
#pragma unroll
      for (int rg = 0; rg < 4; ++rg) {
        const int m = m0 + mt * 16 + quad * 4 + rg;
        float s[4];
#pragma unroll
        for (int nt = 0; nt < 4; ++nt) {
          float vsc = sc[nt][rg] * SCL2;
          // -3e38 (not -1e30): all-masked rows (m=0) must give p==0 exactly
          if (lastt) vsc = (n0 + nt * 16 + l15 < m) ? vsc : -3.0e38f;
          s[nt] = vsc;
        }
        float tm = fmaxf(fmaxf(s[0], s[1]), fmaxf(s[2], s[3]));
        tm = fmaxf(tm, __shfl_xor(tm, 1));
        tm = fmaxf(tm, __shfl_xor(tm, 2));
        tm = fmaxf(tm, __shfl_xor(tm, 4));
        tm = fmaxf(tm, __shfl_xor(tm, 8));
        const float mnew = fmaxf(mrun[mt][rg], tm);
        const float alpha = exp2f(mrun[mt][rg] - mnew);
        float p[4], ps = 0.f;
#pragma unroll
        for (int nt = 0; nt < 4; ++nt) { p[nt] = exp2f(s[nt] - mnew); ps += p[nt]; }
        ps += __shfl_xor(ps, 1);
        ps += __shfl_xor(ps, 2);
        ps += __shfl_xor(ps, 4);
        ps += __shfl_xor(ps, 8);
        lrun[mt][rg] = lrun[mt][rg] * alpha + ps;
        mrun[mt][rg] = mnew;
#pragma unroll
        for (int ntv = 0; ntv < 4; ++ntv) o[mt][ntv][rg] *= alpha;
        // P store at swizzled key pos l15*4+nt (8B, lane-contiguous)
        f16x4 pk;
        pk.x = (f16)p[0]; pk.y = (f16)p[1]; pk.z = (f16)p[2]; pk.w = (f16)p[3];
        *(f16x4*)&lp[w][mt][(quad * 4 + rg) * 72 + l15 * 4] = pk;
      }
    }
    // PV (same-wave LDS produce->consume; compiler inserts lgkmcnt)
#pragma unroll
    for (int mt = 0; mt < 2; ++mt) {
      const f16x8 ap0 = ld8(&lp[w][mt][l15 * 72 + quad * 8]);
      const f16x8 ap1 = ld8(&lp[w][mt][l15 * 72 + 32 + quad * 8]);
#pragma unroll
      for (int ntv = 0; ntv < 4; ++ntv) {
        f32x4 c = MFMA16(ap0, bv0[ntv], o[mt][ntv]);
        o[mt][ntv] = MFMA16(ap1, bv1[ntv], c);
      }
    }
  }

  // write unnormalized partials (merged by attn_diag_kernel)
#pragma unroll
  for (int mt = 0; mt < 2; ++mt)
#pragma unroll
    for (int rg = 0; rg < 4; ++rg) {
      const int i = 4 * (m0 + mt * 16 + quad * 4 + rg) + r;
      const size_t idx = (size_t)bh * 1024 + i;
#pragma unroll
      for (int ntv = 0; ntv < 4; ++ntv)
        po[idx * 64 + ntv * 16 + l15] = o[mt][ntv][rg];
      if (l15 == 0) { ml[idx * 2] = mrun[mt][rg]; ml[idx * 2 + 1] = lrun[mt][rg]; }
    }
}

// ---------------- diagonal band (d=0..3) + merge with far partials -----------
__global__ __launch_bounds__(256) void attn_diag_kernel(
    const f16* __restrict__ qh, const f16* __restrict__ kh, const f16* __restrict__ vh,
    const float* __restrict__ po, const float* __restrict__ ml, f16* __restrict__ ao) {
  const int t = threadIdx.x;
  const int widx = blockIdx.x * 4 + (t >> 6);
  const int l = t & 63;
  const int bh = widx >> 10, i = widx & 1023;
  const float SCL2 = 0.125f * 1.44269504f;

  const float q = (float)qh[(size_t)bh * 65536 + (size_t)i * 64 + l];
  float s[4];
#pragma unroll
  for (int d = 0; d < 4; ++d) {
    const int j = i - d;
    const int jc = j < 0 ? 0 : j;
    float pr = q * (float)kh[(size_t)bh * 65536 + (size_t)jc * 64 + l];
    pr += __shfl_xor(pr, 1);
    pr += __shfl_xor(pr, 2);
    pr += __shfl_xor(pr, 4);
    pr += __shfl_xor(pr, 8);
    pr += __shfl_xor(pr, 16);
    pr += __shfl_xor(pr, 32);
    s[d] = (j >= 0) ? pr * SCL2 : -3.0e38f;
  }
  const float md = fmaxf(fmaxf(s[0], s[1]), fmaxf(s[2], s[3]));
  const size_t idx = (size_t)bh * 1024 + i;
  const float mf = ml[idx * 2], lf = ml[idx * 2 + 1];
  const float M = fmaxf(md, mf);
  float p[4], ld = 0.f;
#pragma unroll
  for (int d = 0; d < 4; ++d) { p[d] = exp2f(s[d] - M); ld += p[d]; }
  float ov = 0.f;
#pragma unroll
  for (int d = 0; d < 4; ++d) {
    const int jc = (i - d) < 0 ? 0 : (i - d);
    ov += p[d] * (float)vh[(size_t)bh * 65536 + (size_t)jc * 64 + l];
  }
  const float fs = exp2f(mf - M);  // mf=-1e30 (empty far set) -> 0
  const float lt = lf * fs + ld;
  const float of = po[idx * 64 + l];
  const float res = (of * fs + ov) / lt;
  const int b = bh >> 4, h = bh & 15;
  ao[((size_t)(b * 1024 + i)) * 1024 + h * 64 + l] = (f16)res;
}

// ---------------------------------------------------------------------------
extern "C" void kernel_launch(void* const* d_in, const int* in_sizes, int n_in,
                              void* d_out, int out_size, void* d_ws, size_t ws_size,
                              hipStream_t stream) {
  const float* Q = (const float*)d_in[0];
  const float* K = (const float*)d_in[1];
  const float* V = (const float*)d_in[2];
  const float* Wq = (const float*)d_in[3];
  const float* bq = (const float*)d_in[4];
  const float* Wk = (const float*)d_in[5];
  const float* bk = (const float*)d_in[6];
  const float* Wv = (const float*)d_in[7];
  const float* bv = (const float*)d_in[8];
  const float* Wo = (const float*)d_in[9];
  const float* bo = (const float*)d_in[10];
  float* out = (float*)d_out;

  char* ws = (char*)d_ws;
  const size_t MB = 1ull << 20;
  // Live-range-overlapped layout, 64 MB total:
  f16* TWo = (f16*)(ws + 0 * MB);      // live until out-proj
  f16* TWq = (f16*)(ws + 2 * MB);      // dead after QKV gemm
  f16* TWk = (f16*)(ws + 4 * MB);
  f16* TWv = (f16*)(ws + 6 * MB);
  f16* Xq  = (f16*)(ws + 8 * MB);      // dead after QKV gemm
  f16* Xk  = (f16*)(ws + 16 * MB);
  f16* Xv  = (f16*)(ws + 24 * MB);
  f16* qhb = (f16*)(ws + 32 * MB);     // [bh][s][64]     (far + diag)
  f16* khb = (f16*)(ws + 40 * MB);     // [bh][s][64]     (far + diag)
  f16* vhb = (f16*)(ws + 48 * MB);     // [bh][s][64]     (diag)
  f16* vtg = (f16*)(ws + 56 * MB);     // [bh][r][d][swz] (far; dead after)
  float* po  = (float*)(ws + 8 * MB);  // 16 MB over dead Xq+Xk (post-QKV)
  float* mlb = (float*)(ws + 24 * MB); // 0.5 MB over dead Xv head
  f16* aob   = (f16*)(ws + 56 * MB);   // 8 MB over vtg (dead post-far)

  prep_kernel<<<dim3(7168), 256, 0, stream>>>(
      Q, K, V, Wq, Wk, Wv, Wo, Xq, Xk, Xv, TWq, TWk, TWv, TWo);
  gemm_qkv_kernel<<<dim3(32, 8, 3), 256, 0, stream>>>(
      Xq, Xk, Xv, TWq, TWk, TWv, bq, bk, bv, qhb, khb, vhb, vtg);
  attn_far_kernel<<<dim3(512), 256, 0, stream>>>(qhb, khb, vtg, po, mlb);
  attn_diag_kernel<<<dim3(16384), 256, 0, stream>>>(qhb, khb, vhb, po, mlb, aob);
  gemm_out_kernel<<<dim3(64, 8), 256, 0, stream>>>(aob, TWo, bo, out);
}

// Round 8
// 226.982 us; speedup vs baseline: 1.0525x; 1.0525x over previous
//
#include <hip/hip_runtime.h>

typedef _Float16 f16;
typedef __attribute__((ext_vector_type(8))) _Float16 f16x8;
typedef __attribute__((ext_vector_type(4))) _Float16 f16x4;
typedef __attribute__((ext_vector_type(4))) float f32x4;

#define MFMA16(a, b, c) __builtin_amdgcn_mfma_f32_16x16x32_f16((a), (b), (c), 0, 0, 0)

// async global->LDS, 16B per lane. LDS base must be WAVE-UNIFORM; HW scatters
// lane i's 16B to base + i*16 (m97/m104).
__device__ __forceinline__ void gld_lds16(const void* g, void* l) {
  __builtin_amdgcn_global_load_lds(
      (__attribute__((address_space(1))) void*)const_cast<void*>(g),
      (__attribute__((address_space(3))) void*)l, 16, 0, 0);
}

__device__ __forceinline__ f16x8 ld8(const f16* p) { return *(const f16x8*)p; }

// ---------------- fp32 -> fp16 elementwise (Q,K,V) -- R3-exact ---------------
__global__ __launch_bounds__(256) void cvt_x_kernel(
    const float* __restrict__ Q, const float* __restrict__ K, const float* __restrict__ V,
    f16* __restrict__ oq, f16* __restrict__ ok, f16* __restrict__ ov) {
  const float* src = blockIdx.z == 0 ? Q : (blockIdx.z == 1 ? K : V);
  f16* dst = blockIdx.z == 0 ? oq : (blockIdx.z == 1 ? ok : ov);
  size_t i = ((size_t)blockIdx.x * 256 + threadIdx.x) * 4;
  float4 f = *(const float4*)(src + i);
  f16x4 o4;
  o4.x = (f16)f.x; o4.y = (f16)f.y; o4.z = (f16)f.z; o4.w = (f16)f.w;
  *(f16x4*)(dst + i) = o4;
}

// ---------------- W [K=1024][N=1024] fp32 -> WT [N][K] fp16 -- R3-exact ------
__global__ __launch_bounds__(256) void cvt_wT_kernel(
    const float* __restrict__ Wq, const float* __restrict__ Wk,
    const float* __restrict__ Wv, const float* __restrict__ Wo,
    f16* __restrict__ Tq, f16* __restrict__ Tk, f16* __restrict__ Tv, f16* __restrict__ To) {
  const int z = blockIdx.z;
  const float* W = z == 0 ? Wq : (z == 1 ? Wk : (z == 2 ? Wv : Wo));
  f16* T = z == 0 ? Tq : (z == 1 ? Tk : (z == 2 ? Tv : To));
  __shared__ float tile[64][65];
  const int k0 = blockIdx.x * 64, n0 = blockIdx.y * 64;
  const int tx = threadIdx.x & 63, ty = threadIdx.x >> 6;
#pragma unroll
  for (int rr = 0; rr < 16; ++rr) {
    int r = rr * 4 + ty;
    tile[r][tx] = W[(size_t)(k0 + r) * 1024 + n0 + tx];
  }
  __syncthreads();
#pragma unroll
  for (int rr = 0; rr < 16; ++rr) {
    int nn = rr * 4 + ty;
    T[(size_t)(n0 + nn) * 1024 + k0 + tx] = (f16)tile[tx][nn];
  }
}

// ---------------- QKV GEMM -- R3-exact (templated, 128x128, kh plain) --------
template <bool QKV>
__global__ __launch_bounds__(256) void gemm_bt_kernel(
    const f16* __restrict__ A0, const f16* __restrict__ A1, const f16* __restrict__ A2,
    const f16* __restrict__ B0, const f16* __restrict__ B1, const f16* __restrict__ B2,
    const float* __restrict__ bias0, const float* __restrict__ bias1, const float* __restrict__ bias2,
    f16* __restrict__ C0, f16* __restrict__ C1, f16* __restrict__ C2,
    f16* __restrict__ C3, float* __restrict__ Cf) {
  const int z = blockIdx.z;
  const f16* A = z == 0 ? A0 : (z == 1 ? A1 : A2);
  const f16* Bt = z == 0 ? B0 : (z == 1 ? B1 : B2);
  const float* bias = z == 0 ? bias0 : (z == 1 ? bias1 : bias2);

  __shared__ alignas(16) f16 lA[128 * 32];
  __shared__ alignas(16) f16 lB[128 * 32];

  const int t = threadIdx.x;
  const int w = t >> 6, lane = t & 63, quad = lane >> 4, l15 = lane & 15;
  const int wm = w >> 1, wn = w & 1;
  const int mbase = blockIdx.x * 128;
  const int nbase = blockIdx.y * 128;

  const f32x4 zero4 = {0.f, 0.f, 0.f, 0.f};
  f32x4 acc[4][4];
#pragma unroll
  for (int mi = 0; mi < 4; ++mi)
#pragma unroll
    for (int ni = 0; ni < 4; ++ni) acc[mi][ni] = zero4;

  const int r = t >> 2;
  const int koff = (t & 3) * 8;

  for (int k0 = 0; k0 < 1024; k0 += 32) {
    __syncthreads();
    gld_lds16(A + (size_t)(mbase + r) * 1024 + k0 + koff, (char*)lA + w * 1024);
    gld_lds16(A + (size_t)(mbase + 64 + r) * 1024 + k0 + koff, (char*)lA + 4096 + w * 1024);
    gld_lds16(Bt + (size_t)(nbase + r) * 1024 + k0 + koff, (char*)lB + w * 1024);
    gld_lds16(Bt + (size_t)(nbase + 64 + r) * 1024 + k0 + koff, (char*)lB + 4096 + w * 1024);
    __syncthreads();

    f16x8 af[4], bf[4];
#pragma unroll
    for (int mi = 0; mi < 4; ++mi)
      af[mi] = ld8(&lA[(wm * 64 + mi * 16 + l15) * 32 + quad * 8]);
#pragma unroll
    for (int ni = 0; ni < 4; ++ni)
      bf[ni] = ld8(&lB[(wn * 64 + ni * 16 + l15) * 32 + quad * 8]);
#pragma unroll
    for (int mi = 0; mi < 4; ++mi)
#pragma unroll
      for (int ni = 0; ni < 4; ++ni)
        acc[mi][ni] = MFMA16(af[mi], bf[ni], acc[mi][ni]);
  }

  // epilogue. C/D layout: col=lane&15, row=quad*4+reg (m89/m91).
#pragma unroll
  for (int mi = 0; mi < 4; ++mi) {
#pragma unroll
    for (int ni = 0; ni < 4; ++ni) {
#pragma unroll
      for (int rg = 0; rg < 4; ++rg) {
        const int row = mbase + wm * 64 + mi * 16 + quad * 4 + rg;
        const int col = nbase + wn * 64 + ni * 16 + l15;
        const float v = acc[mi][ni][rg] + bias[col];
        if (QKV) {
          const int bh = (row >> 10) * 16 + (col >> 6);
          const int s = row & 1023, d = col & 63;
          const f16 hv = (f16)v;
          if (z != 2) {
            f16* Ch = (z == 0) ? C0 : C1;
            Ch[(size_t)bh * 65536 + s * 64 + d] = hv;
          } else {
            C2[(size_t)bh * 65536 + s * 64 + d] = hv;
            // vtg: class r = s&3, class-pos n = s>>2; 64-block swizzle
            // n -> (n&15)*4 + ((n&63)>>4) so P stores / B-frag reads vectorize.
            const int rr = s & 3, n = s >> 2, wi = n & 63;
            C3[(size_t)bh * 65536 + (size_t)rr * 16384 + (size_t)d * 256 +
               (n & ~63) + ((wi & 15) << 2) + (wi >> 4)] = hv;
          }
        } else {
          Cf[(size_t)row * 1024 + col] = v;
        }
      }
    }
  }
}

// ---------------- out-projection GEMM: 64x128 tile, 512 blocks ---------------
// THE ONE CHANGE vs R3 (was 128x128 @ 256 blocks = 1 block/CU).
__global__ __launch_bounds__(256) void gemm_out_kernel(
    const f16* __restrict__ A, const f16* __restrict__ Bt,
    const float* __restrict__ bias, float* __restrict__ Cf) {
  __shared__ alignas(16) f16 lA[64 * 32];
  __shared__ alignas(16) f16 lB[128 * 32];

  const int t = threadIdx.x;
  const int w = t >> 6, lane = t & 63, quad = lane >> 4, l15 = lane & 15;
  const int wm = w >> 1, wn = w & 1;  // wave tile 32m x 64n
  const int mbase = blockIdx.x * 64;
  const int nbase = blockIdx.y * 128;

  const f32x4 zero4 = {0.f, 0.f, 0.f, 0.f};
  f32x4 acc[2][4];
#pragma unroll
  for (int mi = 0; mi < 2; ++mi)
#pragma unroll
    for (int ni = 0; ni < 4; ++ni) acc[mi][ni] = zero4;

  const int r = t >> 2;
  const int koff = (t & 3) * 8;

  for (int k0 = 0; k0 < 1024; k0 += 32) {
    __syncthreads();
    gld_lds16(A + (size_t)(mbase + r) * 1024 + k0 + koff, (char*)lA + w * 1024);
    gld_lds16(Bt + (size_t)(nbase + r) * 1024 + k0 + koff, (char*)lB + w * 1024);
    gld_lds16(Bt + (size_t)(nbase + 64 + r) * 1024 + k0 + koff, (char*)lB + 4096 + w * 1024);
    __syncthreads();

    f16x8 af[2], bf[4];
#pragma unroll
    for (int mi = 0; mi < 2; ++mi)
      af[mi] = ld8(&lA[(wm * 32 + mi * 16 + l15) * 32 + quad * 8]);
#pragma unroll
    for (int ni = 0; ni < 4; ++ni)
      bf[ni] = ld8(&lB[(wn * 64 + ni * 16 + l15) * 32 + quad * 8]);
#pragma unroll
    for (int mi = 0; mi < 2; ++mi)
#pragma unroll
      for (int ni = 0; ni < 4; ++ni)
        acc[mi][ni] = MFMA16(af[mi], bf[ni], acc[mi][ni]);
  }

#pragma unroll
  for (int mi = 0; mi < 2; ++mi)
#pragma unroll
    for (int ni = 0; ni < 4; ++ni)
#pragma unroll
      for (int rg = 0; rg < 4; ++rg) {
        const int row = mbase + wm * 32 + mi * 16 + quad * 4 + rg;
        const int col = nbase + wn * 64 + ni * 16 + l15;
        Cf[(size_t)row * 1024 + col] = acc[mi][ni][rg] + bias[col];
      }
}

// ---------------- far-field attention -- R3-exact ----------------------------
__global__ __launch_bounds__(256) void attn_far_kernel(
    const f16* __restrict__ qh, const f16* __restrict__ kh,
    const f16* __restrict__ vtg, float* __restrict__ po, float* __restrict__ ml) {
  const int t = threadIdx.x;
  const int w = t >> 6, lane = t & 63, quad = lane >> 4, l15 = lane & 15;
  const int widx = blockIdx.x + 512 * w;
  const int bh = (widx & 255) >> 2, r = widx & 3;
  const int wq = widx >> 8;          // 0..7, 32 class-rows each
  const int m0 = wq * 32;
  const int ntiles = (wq >> 1) + 1;  // key tiles covering n < m0+32

  __shared__ alignas(16) f16 lp[4][2][16 * 72];

  const f16* qb = qh + (size_t)bh * 65536;
  const f16* kb = kh + (size_t)bh * 65536;
  const f16* vb = vtg + (size_t)bh * 65536 + (size_t)r * 16384;  // [d][swz n]
  const float SCL2 = 0.125f * 1.44269504f;  // 1/sqrt(64) * log2(e)

  f16x8 aq[2][2];
#pragma unroll
  for (int mt = 0; mt < 2; ++mt) {
    const int i = 4 * (m0 + mt * 16 + l15) + r;
#pragma unroll
    for (int ko = 0; ko < 2; ++ko)
      aq[mt][ko] = ld8(qb + (size_t)i * 64 + ko * 32 + quad * 8);
  }

  const f32x4 zero4 = {0.f, 0.f, 0.f, 0.f};
  f32x4 o[2][4];
  float mrun[2][4], lrun[2][4];
#pragma unroll
  for (int mt = 0; mt < 2; ++mt)
#pragma unroll
    for (int i = 0; i < 4; ++i) {
      o[mt][i] = zero4; mrun[mt][i] = -1e30f; lrun[mt][i] = 0.f;
    }

  for (int jt = 0; jt < ntiles; ++jt) {
    const int n0 = jt * 64;
    f16x8 bk0[4], bk1[4], bv0[4], bv1[4];
#pragma unroll
    for (int nt = 0; nt < 4; ++nt) {
      const f16* kr = kb + (size_t)(4 * (n0 + nt * 16 + l15) + r) * 64;
      bk0[nt] = ld8(kr + quad * 8);
      bk1[nt] = ld8(kr + 32 + quad * 8);
      const f16* vr = vb + (size_t)(nt * 16 + l15) * 256 + n0;  // swizzled keys
      bv0[nt] = ld8(vr + quad * 8);
      bv1[nt] = ld8(vr + 32 + quad * 8);
    }
    const bool lastt = (jt == ntiles - 1);  // only tile needing the n<m mask
#pragma unroll
    for (int mt = 0; mt < 2; ++mt) {
      f32x4 sc[4];
#pragma unroll
      for (int nt = 0; nt < 4; ++nt) {
        f32x4 c = MFMA16(aq[mt][0], bk0[nt], zero4);
        sc[nt] = MFMA16(aq[mt][1], bk1[nt], c);
      }
#pragma unroll
      for (int rg = 0; rg < 4; ++rg) {
        const int m = m0 + mt * 16 + quad * 4 + rg;
        float s[4];
#pragma unroll
        for (int nt = 0; nt < 4; ++nt) {
          float vsc = sc[nt][rg] * SCL2;
          // -3e38 (not -1e30): all-masked rows (m=0) must give p==0 exactly
          if (lastt) vsc = (n0 + nt * 16 + l15 < m) ? vsc : -3.0e38f;
          s[nt] = vsc;
        }
        float tm = fmaxf(fmaxf(s[0], s[1]), fmaxf(s[2], s[3]));
        tm = fmaxf(tm, __shfl_xor(tm, 1));
        tm = fmaxf(tm, __shfl_xor(tm, 2));
        tm = fmaxf(tm, __shfl_xor(tm, 4));
        tm = fmaxf(tm, __shfl_xor(tm, 8));
        const float mnew = fmaxf(mrun[mt][rg], tm);
        const float alpha = exp2f(mrun[mt][rg] - mnew);
        float p[4], ps = 0.f;
#pragma unroll
        for (int nt = 0; nt < 4; ++nt) { p[nt] = exp2f(s[nt] - mnew); ps += p[nt]; }
        ps += __shfl_xor(ps, 1);
        ps += __shfl_xor(ps, 2);
        ps += __shfl_xor(ps, 4);
        ps += __shfl_xor(ps, 8);
        lrun[mt][rg] = lrun[mt][rg] * alpha + ps;
        mrun[mt][rg] = mnew;
#pragma unroll
        for (int ntv = 0; ntv < 4; ++ntv) o[mt][ntv][rg] *= alpha;
        f16x4 pk;
        pk.x = (f16)p[0]; pk.y = (f16)p[1]; pk.z = (f16)p[2]; pk.w = (f16)p[3];
        *(f16x4*)&lp[w][mt][(quad * 4 + rg) * 72 + l15 * 4] = pk;
      }
    }
    // PV (same-wave LDS produce->consume; compiler inserts lgkmcnt)
#pragma unroll
    for (int mt = 0; mt < 2; ++mt) {
      const f16x8 ap0 = ld8(&lp[w][mt][l15 * 72 + quad * 8]);
      const f16x8 ap1 = ld8(&lp[w][mt][l15 * 72 + 32 + quad * 8]);
#pragma unroll
      for (int ntv = 0; ntv < 4; ++ntv) {
        f32x4 c = MFMA16(ap0, bv0[ntv], o[mt][ntv]);
        o[mt][ntv] = MFMA16(ap1, bv1[ntv], c);
      }
    }
  }

  // write unnormalized partials (merged by attn_diag_kernel)
#pragma unroll
  for (int mt = 0; mt < 2; ++mt)
#pragma unroll
    for (int rg = 0; rg < 4; ++rg) {
      const int i = 4 * (m0 + mt * 16 + quad * 4 + rg) + r;
      const size_t idx = (size_t)bh * 1024 + i;
#pragma unroll
      for (int ntv = 0; ntv < 4; ++ntv)
        po[idx * 64 + ntv * 16 + l15] = o[mt][ntv][rg];
      if (l15 == 0) { ml[idx * 2] = mrun[mt][rg]; ml[idx * 2 + 1] = lrun[mt][rg]; }
    }
}

// ---------------- diagonal band (d=0..3) + merge -- R3-exact -----------------
__global__ __launch_bounds__(256) void attn_diag_kernel(
    const f16* __restrict__ qh, const f16* __restrict__ kh, const f16* __restrict__ vh,
    const float* __restrict__ po, const float* __restrict__ ml, f16* __restrict__ ao) {
  const int t = threadIdx.x;
  const int widx = blockIdx.x * 4 + (t >> 6);
  const int l = t & 63;
  const int bh = widx >> 10, i = widx & 1023;
  const float SCL2 = 0.125f * 1.44269504f;

  const float q = (float)qh[(size_t)bh * 65536 + (size_t)i * 64 + l];
  float s[4];
#pragma unroll
  for (int d = 0; d < 4; ++d) {
    const int j = i - d;
    const int jc = j < 0 ? 0 : j;
    float pr = q * (float)kh[(size_t)bh * 65536 + (size_t)jc * 64 + l];
    pr += __shfl_xor(pr, 1);
    pr += __shfl_xor(pr, 2);
    pr += __shfl_xor(pr, 4);
    pr += __shfl_xor(pr, 8);
    pr += __shfl_xor(pr, 16);
    pr += __shfl_xor(pr, 32);
    s[d] = (j >= 0) ? pr * SCL2 : -3.0e38f;
  }
  const float md = fmaxf(fmaxf(s[0], s[1]), fmaxf(s[2], s[3]));
  const size_t idx = (size_t)bh * 1024 + i;
  const float mf = ml[idx * 2], lf = ml[idx * 2 + 1];
  const float M = fmaxf(md, mf);
  float p[4], ld = 0.f;
#pragma unroll
  for (int d = 0; d < 4; ++d) { p[d] = exp2f(s[d] - M); ld += p[d]; }
  float ov = 0.f;
#pragma unroll
  for (int d = 0; d < 4; ++d) {
    const int jc = (i - d) < 0 ? 0 : (i - d);
    ov += p[d] * (float)vh[(size_t)bh * 65536 + (size_t)jc * 64 + l];
  }
  const float fs = exp2f(mf - M);  // mf=-1e30 (empty far set) -> 0
  const float lt = lf * fs + ld;
  const float of = po[idx * 64 + l];
  const float res = (of * fs + ov) / lt;
  const int b = bh >> 4, h = bh & 15;
  ao[((size_t)(b * 1024 + i)) * 1024 + h * 64 + l] = (f16)res;
}

// ---------------------------------------------------------------------------
extern "C" void kernel_launch(void* const* d_in, const int* in_sizes, int n_in,
                              void* d_out, int out_size, void* d_ws, size_t ws_size,
                              hipStream_t stream) {
  const float* Q = (const float*)d_in[0];
  const float* K = (const float*)d_in[1];
  const float* V = (const float*)d_in[2];
  const float* Wq = (const float*)d_in[3];
  const float* bq = (const float*)d_in[4];
  const float* Wk = (const float*)d_in[5];
  const float* bk = (const float*)d_in[6];
  const float* Wv = (const float*)d_in[7];
  const float* bv = (const float*)d_in[8];
  const float* Wo = (const float*)d_in[9];
  const float* bo = (const float*)d_in[10];
  float* out = (float*)d_out;

  char* ws = (char*)d_ws;
  const size_t MB = 1ull << 20;
  // R3-exact layout:
  f16* Xq  = (f16*)(ws + 0 * MB);
  f16* Xk  = (f16*)(ws + 8 * MB);
  f16* Xv  = (f16*)(ws + 16 * MB);
  f16* TWq = (f16*)(ws + 24 * MB);
  f16* TWk = (f16*)(ws + 26 * MB);
  f16* TWv = (f16*)(ws + 28 * MB);
  f16* TWo = (f16*)(ws + 30 * MB);
  f16* qhb = (f16*)(ws + 32 * MB);
  f16* khb = (f16*)(ws + 40 * MB);
  f16* vhb = (f16*)(ws + 48 * MB);
  f16* vtg = (f16*)(ws + 56 * MB);
  float* po  = (float*)(ws + 0 * MB);
  float* mlb = (float*)(ws + 16 * MB);
  f16* aob   = (f16*)(ws + 17 * MB);

  cvt_x_kernel<<<dim3(4096, 1, 3), 256, 0, stream>>>(Q, K, V, Xq, Xk, Xv);
  cvt_wT_kernel<<<dim3(16, 16, 4), 256, 0, stream>>>(Wq, Wk, Wv, Wo, TWq, TWk, TWv, TWo);
  gemm_bt_kernel<true><<<dim3(32, 8, 3), 256, 0, stream>>>(
      Xq, Xk, Xv, TWq, TWk, TWv, bq, bk, bv, qhb, khb, vhb, vtg, nullptr);
  attn_far_kernel<<<dim3(512), 256, 0, stream>>>(qhb, khb, vtg, po, mlb);
  attn_diag_kernel<<<dim3(16384), 256, 0, stream>>>(qhb, khb, vhb, po, mlb, aob);
  gemm_out_kernel<<<dim3(64, 8), 256, 0, stream>>>(aob, TWo, bo, out);
}